// Round 6
// baseline (181.832 us; speedup 1.0000x reference)
//
#include <hip/hip_runtime.h>

#define NVOC 65
#define NE   32
#define HD   16
#define NB   65536
#define NROWS (NB * 8)                   // 524288
#define NLOG  (NROWS * NVOC)             // 34078720

// ws layout (floats): wsTab = ws+16 (64B aligned), 10074 floats:
//   G1@0(4225) TVL@4225(4225) G2@8450(520) G3@8970(520) G4@9490(64) PVL@9554(520)
// block partials: ws[10112 .. 10112+1024)

static __device__ __forceinline__ float readlane_f(float v, int l) {
  return __uint_as_float(__builtin_amdgcn_readlane(__float_as_uint(v), l));
}
static __device__ __forceinline__ float readfirst_f(float v) {
  return __uint_as_float(__builtin_amdgcn_readfirstlane(__float_as_uint(v)));
}

// ---- tables kernel: 16 blocks x 1024 threads; each block stages weights +
//      projections redundantly (tiny), computes a 632-entry slice of the tables.
__global__ __launch_bounds__(1024) void bigram_tables(
    const float* __restrict__ tok, const float* __restrict__ pos,
    const float* __restrict__ Wk, const float* __restrict__ bk,
    const float* __restrict__ Wq, const float* __restrict__ bq,
    const float* __restrict__ Wv, const float* __restrict__ bv,
    const float* __restrict__ Wlm, float* __restrict__ ws)
{
  // LDS: tok@0(2080) pos@2080(256) Wq@2336(512) Wk@2848(512) Wv@3360(512)
  //      Wlm@3872(1040) TQ@4912(1040) TK@5952(1040) TV@6992(1040)
  //      PQ@8032(128) PK@8160(128) PV@8288(128)  -> 8416 floats
  __shared__ float S[8416];
  const int tid = threadIdx.x;
  const int bid = blockIdx.x;
  for (int o = tid; o < 2080; o += 1024) S[o] = tok[o];
  for (int o = tid; o < 256;  o += 1024) S[2080 + o] = pos[o];
  for (int o = tid; o < 512;  o += 1024) {
    S[2336 + o] = Wq[o]; S[2848 + o] = Wk[o]; S[3360 + o] = Wv[o];
  }
  for (int o = tid; o < 1040; o += 1024) S[3872 + o] = Wlm[o];
  __syncthreads();

  for (int o = tid; o < 1168; o += 1024) {
    if (o < 1040) {
      const int a = o >> 4, h = o & 15;
      float sq = 0.f, sk = 0.f, sv = 0.f;
      #pragma unroll
      for (int c = 0; c < NE; ++c) {
        const float e = S[a*32 + c];
        sq = fmaf(e, S[2336 + c*16 + h], sq);
        sk = fmaf(e, S[2848 + c*16 + h], sk);
        sv = fmaf(e, S[3360 + c*16 + h], sv);
      }
      S[4912 + o] = sq; S[5952 + o] = sk; S[6992 + o] = sv;
    } else {
      const int o2 = o - 1040, t = o2 >> 4, h = o2 & 15;
      float sq = bq[h], sk = bk[h], sv = bv[h];
      #pragma unroll
      for (int c = 0; c < NE; ++c) {
        const float e = S[2080 + t*32 + c];
        sq = fmaf(e, S[2336 + c*16 + h], sq);
        sk = fmaf(e, S[2848 + c*16 + h], sk);
        sv = fmaf(e, S[3360 + c*16 + h], sv);
      }
      S[8032 + o2] = sq; S[8160 + o2] = sk; S[8288 + o2] = sv;
    }
  }
  __syncthreads();

  float* wsTab = ws + 16;
  const int lo = bid * 632;
  const int hi = (lo + 632 < 10074) ? lo + 632 : 10074;
  for (int o = lo + tid; o < hi; o += 1024) {
    float r = 0.f; int dst;
    if (o < 4225) {                       // G1[a][b] = 0.25 * TQ[a].TK[b]
      const int a = o / 65, b = o % 65;
      #pragma unroll
      for (int h = 0; h < HD; ++h) r = fmaf(S[4912 + a*16 + h], S[5952 + b*16 + h], r);
      r *= 0.25f; dst = o;
    } else if (o < 4745) {                // G2[a][s]
      const int o2 = o - 4225, a = o2 >> 3, s2 = o2 & 7;
      #pragma unroll
      for (int h = 0; h < HD; ++h) r = fmaf(S[4912 + a*16 + h], S[8160 + s2*16 + h], r);
      r *= 0.25f; dst = 8450 + o2;
    } else if (o < 5265) {                // G3[t][b]
      const int o2 = o - 4745, t2 = o2 / 65, b = o2 % 65;
      #pragma unroll
      for (int h = 0; h < HD; ++h) r = fmaf(S[8032 + t2*16 + h], S[5952 + b*16 + h], r);
      r *= 0.25f; dst = 8970 + o2;
    } else if (o < 5329) {                // G4[t][s]
      const int o2 = o - 5265, t2 = o2 >> 3, s2 = o2 & 7;
      #pragma unroll
      for (int h = 0; h < HD; ++h) r = fmaf(S[8032 + t2*16 + h], S[8160 + s2*16 + h], r);
      r *= 0.25f; dst = 9490 + o2;
    } else if (o < 9554) {                // TVL[a][j]
      const int o2 = o - 5329, a = o2 / 65, j = o2 % 65;
      #pragma unroll
      for (int h = 0; h < HD; ++h) r = fmaf(S[6992 + a*16 + h], S[3872 + h*65 + j], r);
      dst = 4225 + o2;
    } else {                              // PVL[s][j]
      const int o2 = o - 9554, s2 = o2 / 65, j = o2 % 65;
      #pragma unroll
      for (int h = 0; h < HD; ++h) r = fmaf(S[8288 + s2*16 + h], S[3872 + h*65 + j], r);
      dst = o;
    }
    wsTab[dst] = r;
  }
}

// ---- main kernel: 1024 blocks x 512 threads; 1 wave handles 8 batches ----
// LDS = 40.3 KB -> 4 blocks/CU (32 waves/CU). Two-level software pipeline:
//  - itb+1's score/softmax chain overlaps itb's P.V (round 4)
//  - itb-1's row-sum reduction+log overlaps itb's LDS reads (this round):
//    the 13-level shfl fold runs under ds_read latency instead of at the tail.
__global__ __launch_bounds__(512, 8) void bigram_main(
    const int* __restrict__ idx, const int* __restrict__ tgt,
    const float* __restrict__ blm, const float* __restrict__ ws,
    float* __restrict__ wsout, float* __restrict__ out)
{
  __shared__ __align__(16) float S[10074];
  __shared__ float red[8];
  const int tid = threadIdx.x;
  const int lane = tid & 63;
  const int w    = tid >> 6;                 // 0..7
  const int t    = lane >> 3;
  const int s    = lane & 7;
  const int u    = lane & 7;
  const int gw = blockIdx.x * 8 + w;         // 8192 waves total
  const int iv = idx[gw*64 + lane];          // element (itb*8+p) lives at lane itb*8+p
  const int tv = tgt[gw*64 + lane];
  const float blmj  = blm[lane];
  const float blm64 = blm[64];
  const float* wsTab = ws + 16;
  {
    const float4* t4 = (const float4*)wsTab;
    float4* s4 = (float4*)S;
    for (int o = tid; o < 2518; o += 512) s4[o] = t4[o];   // 10072 floats
    if (tid < 2) S[10072 + tid] = wsTab[10072 + tid];
  }
  __syncthreads();

  // wave-uniform output base (SGPR) + small 32-bit per-lane voffset
  const int gwu = __builtin_amdgcn_readfirstlane(gw);
  float* __restrict__ outw = out + (size_t)gwu * 4160u;   // 8 itb * 520
  const unsigned l65p64 = (unsigned)lane * 65u + 64u;     // col-64 row offsets
  const bool lane8m = (lane < 8);

  const float g4 = S[9490 + lane];           // G4[t][s], lane == t*8+s
  float pvl[8], pvl64[8];
  #pragma unroll
  for (int k = 0; k < 8; ++k) {
    pvl[k]   = S[9554 + k*65 + lane];        // PVL[s=k][j=lane]
    pvl64[k] = readfirst_f(S[9554 + k*65 + 64]);  // uniform -> SGPR
  }
  const bool b0 = (lane & 1) != 0, b1 = (lane & 2) != 0, b2 = (lane & 4) != 0;

  // prologue: wsm for itb=0
  float wsm_cur;
  {
    const int av  = __shfl(iv, s);
    const int a_t = __shfl(iv, t);
    float wr = S[a_t*65 + av] + S[8450 + a_t*8 + s] + S[8970 + t*65 + av] + g4;
    float e = (t >= s) ? __expf(wr) : 0.f;
    float sm = e;
    sm += __shfl_xor(sm, 8); sm += __shfl_xor(sm, 16); sm += __shfl_xor(sm, 32);
    wsm_cur = __fdividef(e, sm);
  }

  float acc_lsm = 0.f, tl = 0.f;             // tl: per-lane target-logit partial
  float eeP[8];                              // carried: prev itb's exp(logits)
  float lg64P = 0.f;                         // carried: prev itb's col-64 logit
  for (int itb = 0; itb < 8; ++itb) {
    const int base  = itb * 8;
    const int basen = ((itb + 1) & 7) * 8;   // wraps on last iter (result unused)
    // ---- A: issue this itb's LDS reads (results needed only in P.V below) ----
    float ms[8], ms64[8];
    #pragma unroll
    for (int k = 0; k < 8; ++k) {
      const int ak = __builtin_amdgcn_readlane(iv, base + k);
      ms[k]   = S[4225 + ak*65 + lane];
      ms64[k] = S[4225 + ak*65 + 64];
    }
    // ---- B: reduce PREVIOUS itb's row sums under A's ds_read latency ----
    if (itb > 0) {
      float k0 = b0 ? eeP[1] : eeP[0], s0 = b0 ? eeP[0] : eeP[1];
      float k1 = b0 ? eeP[3] : eeP[2], s1 = b0 ? eeP[2] : eeP[3];
      float k2 = b0 ? eeP[5] : eeP[4], s2 = b0 ? eeP[4] : eeP[5];
      float k3 = b0 ? eeP[7] : eeP[6], s3 = b0 ? eeP[6] : eeP[7];
      k0 += __shfl_xor(s0, 1); k1 += __shfl_xor(s1, 1);
      k2 += __shfl_xor(s2, 1); k3 += __shfl_xor(s3, 1);
      float m0 = b1 ? k1 : k0, t0 = b1 ? k0 : k1;
      float m1 = b1 ? k3 : k2, t1 = b1 ? k2 : k3;
      m0 += __shfl_xor(t0, 2); m1 += __shfl_xor(t1, 2);
      float r = b2 ? m1 : m0,  t2 = b2 ? m0 : m1;
      r += __shfl_xor(t2, 4);
      if (lane8m) r += __expf(lg64P);        // col-64 exp once per row
      r += __shfl_xor(r, 8); r += __shfl_xor(r, 16); r += __shfl_xor(r, 32);
      acc_lsm += __log2f(r);
    }
    // ---- C: next itb's score chain (longest latency) ----
    const int av_n  = __shfl(iv, basen + s);
    const int a_tn  = __shfl(iv, basen + t);
    const float wr_n = S[a_tn*65 + av_n] + S[8450 + a_tn*8 + s]
                     + S[8970 + t*65 + av_n] + g4;
    float e_n = (t >= s) ? __expf(wr_n) : 0.f;
    // ---- col-64 logit for row (lane&7); wei[u][k]=0 for k>u so full sum exact
    float lg64v = blm64;
    #pragma unroll
    for (int k = 0; k < 8; ++k) {
      const float wk_row = __shfl(wsm_cur, u*8 + k);
      const float m64k = readfirst_f(ms64[k]) + pvl64[k];  // uniform -> SGPR
      lg64v = fmaf(wk_row, m64k, lg64v);
    }
    float sm_n = e_n;
    sm_n += __shfl_xor(sm_n, 8);             // overlap with P.V below
    const unsigned vo = (unsigned)itb * 520u + (unsigned)lane;
    if (lane8m) outw[(unsigned)itb * 520u + l65p64] = lg64v;
    // col-64 target contribution: row u's target (tg==64) -> lg64v at lane u
    {
      const int tgu = __shfl(tv, base + u);
      tl += (lane8m && tgu == 64) ? lg64v : 0.f;
    }
    // ---- D: P.V for this itb ----
    #pragma unroll
    for (int k = 0; k < 8; ++k) ms[k] += pvl[k];
    #pragma unroll
    for (int tt = 0; tt < 4; ++tt) {
      float lg = blmj;                       // causal: k<=tt only (exact)
      #pragma unroll
      for (int k = 0; k <= tt; ++k) {
        const float wk = readlane_f(wsm_cur, tt*8 + k);
        lg = fmaf(wk, ms[k], lg);
      }
      outw[vo + tt*65] = lg;                 // tt*65*4 folds into inst offset
      eeP[tt] = __expf(lg);
      const int tg = __builtin_amdgcn_readlane(tv, base + tt);
      tl += (lane == tg) ? lg : 0.f;         // each row's target counted once
    }
    sm_n += __shfl_xor(sm_n, 16);
    #pragma unroll
    for (int tt = 4; tt < 8; ++tt) {
      float lg = blmj;
      #pragma unroll
      for (int k = 0; k <= tt; ++k) {
        const float wk = readlane_f(wsm_cur, tt*8 + k);
        lg = fmaf(wk, ms[k], lg);
      }
      outw[vo + tt*65] = lg;
      eeP[tt] = __expf(lg);
      const int tg = __builtin_amdgcn_readlane(tv, base + tt);
      tl += (lane == tg) ? lg : 0.f;
    }
    sm_n += __shfl_xor(sm_n, 32);
    lg64P = lg64v;
    wsm_cur = __fdividef(e_n, sm_n);         // finish next itb's softmax
  }
  // epilogue: reduce itb=7's row sums
  {
    float k0 = b0 ? eeP[1] : eeP[0], s0 = b0 ? eeP[0] : eeP[1];
    float k1 = b0 ? eeP[3] : eeP[2], s1 = b0 ? eeP[2] : eeP[3];
    float k2 = b0 ? eeP[5] : eeP[4], s2 = b0 ? eeP[4] : eeP[5];
    float k3 = b0 ? eeP[7] : eeP[6], s3 = b0 ? eeP[6] : eeP[7];
    k0 += __shfl_xor(s0, 1); k1 += __shfl_xor(s1, 1);
    k2 += __shfl_xor(s2, 1); k3 += __shfl_xor(s3, 1);
    float m0 = b1 ? k1 : k0, t0 = b1 ? k0 : k1;
    float m1 = b1 ? k3 : k2, t1 = b1 ? k2 : k3;
    m0 += __shfl_xor(t0, 2); m1 += __shfl_xor(t1, 2);
    float r = b2 ? m1 : m0,  t2 = b2 ? m0 : m1;
    r += __shfl_xor(t2, 4);
    if (lane8m) r += __expf(lg64P);
    r += __shfl_xor(r, 8); r += __shfl_xor(r, 16); r += __shfl_xor(r, 32);
    acc_lsm += __log2f(r);
  }
  // acc_lsm carries 8 lane-copies per row (coeff ln2/8); tl counted once per row
  float v = acc_lsm * (0.6931471805599453f * 0.125f) - tl;
  v += __shfl_xor(v, 1); v += __shfl_xor(v, 2);  v += __shfl_xor(v, 4);
  v += __shfl_xor(v, 8); v += __shfl_xor(v, 16); v += __shfl_xor(v, 32);
  if (lane == 0) red[w] = v;
  __syncthreads();
  if (tid == 0) {
    // poison-safe: plain store of this block's partial (no atomics, no contention)
    wsout[10112 + blockIdx.x] = red[0] + red[1] + red[2] + red[3]
                              + red[4] + red[5] + red[6] + red[7];
  }
}

// ---- final reduction: sum 1024 block partials -> loss ----
__global__ __launch_bounds__(1024) void bigram_fin2(
    const float* __restrict__ ws, float* __restrict__ out)
{
  __shared__ float r[16];
  const int tid = threadIdx.x;
  float v = ws[10112 + tid];
  v += __shfl_xor(v, 1); v += __shfl_xor(v, 2);  v += __shfl_xor(v, 4);
  v += __shfl_xor(v, 8); v += __shfl_xor(v, 16); v += __shfl_xor(v, 32);
  if ((tid & 63) == 0) r[tid >> 6] = v;
  __syncthreads();
  if (tid == 0) {
    float a = 0.f;
    #pragma unroll
    for (int i = 0; i < 16; ++i) a += r[i];
    out[NLOG] = a * (1.0f / (float)NROWS);
  }
}

extern "C" void kernel_launch(void* const* d_in, const int* in_sizes, int n_in,
                              void* d_out, int out_size, void* d_ws, size_t ws_size,
                              hipStream_t stream) {
  const int* idx = (const int*)d_in[0];
  const int* tgt = (const int*)d_in[1];
  float* ws = (float*)d_ws;
  float* out = (float*)d_out;

  bigram_tables<<<16, 1024, 0, stream>>>((const float*)d_in[2], (const float*)d_in[3],
                                         (const float*)d_in[4], (const float*)d_in[5],
                                         (const float*)d_in[6], (const float*)d_in[7],
                                         (const float*)d_in[8], (const float*)d_in[9],
                                         (const float*)d_in[10], ws);
  bigram_main<<<1024, 512, 0, stream>>>(idx, tgt, (const float*)d_in[11], ws, ws, out);
  bigram_fin2<<<1, 1024, 0, stream>>>(ws, out);
}

// Round 7
// 180.682 us; speedup vs baseline: 1.0064x; 1.0064x over previous
//
#include <hip/hip_runtime.h>

#define NVOC 65
#define NE   32
#define HD   16
#define NB   65536
#define NROWS (NB * 8)                   // 524288
#define NLOG  (NROWS * NVOC)             // 34078720

// ws layout (floats): wsTab = ws+16 (64B aligned), 10074 floats:
//   G1@0(4225) TVL@4225(4225) G2@8450(520) G3@8970(520) G4@9490(64) PVL@9554(520)
// block partials: ws[10112 .. 10112+1024)

static __device__ __forceinline__ float readlane_f(float v, int l) {
  return __uint_as_float(__builtin_amdgcn_readlane(__float_as_uint(v), l));
}
// xor-1 / xor-2 cross-lane via DPP quad_perm (VALU pipe, not DS)
template<int C>
static __device__ __forceinline__ float dppx(float x) {
  return __int_as_float(__builtin_amdgcn_update_dpp(
      __float_as_int(x), __float_as_int(x), C, 0xF, 0xF, true));
}
#define DPP_X1 0xB1   // quad_perm(1,0,3,2) = lane^1
#define DPP_X2 0x4E   // quad_perm(2,3,0,1) = lane^2
// xor-4 / xor-8 via ds_swizzle immediate (DS, but no index VGPR)
template<int P>
static __device__ __forceinline__ float swz(float x) {
  return __int_as_float(__builtin_amdgcn_ds_swizzle(__float_as_int(x), P));
}
#define SWZ_X4 0x101F
#define SWZ_X8 0x201F
// x + x^16 / x + x^32 via gfx950 permlane swaps (VALU pipe, not DS)
static __device__ __forceinline__ float permsum16(float x) {
  auto pr = __builtin_amdgcn_permlane16_swap(__float_as_uint(x),
                                             __float_as_uint(x), false, false);
  return __uint_as_float(pr[0]) + __uint_as_float(pr[1]);
}
static __device__ __forceinline__ float permsum32(float x) {
  auto pr = __builtin_amdgcn_permlane32_swap(__float_as_uint(x),
                                             __float_as_uint(x), false, false);
  return __uint_as_float(pr[0]) + __uint_as_float(pr[1]);
}

// ---- tables kernel: 16 blocks x 1024 threads (unchanged) ----
__global__ __launch_bounds__(1024) void bigram_tables(
    const float* __restrict__ tok, const float* __restrict__ pos,
    const float* __restrict__ Wk, const float* __restrict__ bk,
    const float* __restrict__ Wq, const float* __restrict__ bq,
    const float* __restrict__ Wv, const float* __restrict__ bv,
    const float* __restrict__ Wlm, float* __restrict__ ws)
{
  __shared__ float S[8416];
  const int tid = threadIdx.x;
  const int bid = blockIdx.x;
  for (int o = tid; o < 2080; o += 1024) S[o] = tok[o];
  for (int o = tid; o < 256;  o += 1024) S[2080 + o] = pos[o];
  for (int o = tid; o < 512;  o += 1024) {
    S[2336 + o] = Wq[o]; S[2848 + o] = Wk[o]; S[3360 + o] = Wv[o];
  }
  for (int o = tid; o < 1040; o += 1024) S[3872 + o] = Wlm[o];
  __syncthreads();

  for (int o = tid; o < 1168; o += 1024) {
    if (o < 1040) {
      const int a = o >> 4, h = o & 15;
      float sq = 0.f, sk = 0.f, sv = 0.f;
      #pragma unroll
      for (int c = 0; c < NE; ++c) {
        const float e = S[a*32 + c];
        sq = fmaf(e, S[2336 + c*16 + h], sq);
        sk = fmaf(e, S[2848 + c*16 + h], sk);
        sv = fmaf(e, S[3360 + c*16 + h], sv);
      }
      S[4912 + o] = sq; S[5952 + o] = sk; S[6992 + o] = sv;
    } else {
      const int o2 = o - 1040, t = o2 >> 4, h = o2 & 15;
      float sq = bq[h], sk = bk[h], sv = bv[h];
      #pragma unroll
      for (int c = 0; c < NE; ++c) {
        const float e = S[2080 + t*32 + c];
        sq = fmaf(e, S[2336 + c*16 + h], sq);
        sk = fmaf(e, S[2848 + c*16 + h], sk);
        sv = fmaf(e, S[3360 + c*16 + h], sv);
      }
      S[8032 + o2] = sq; S[8160 + o2] = sk; S[8288 + o2] = sv;
    }
  }
  __syncthreads();

  float* wsTab = ws + 16;
  const int lo = bid * 632;
  const int hi = (lo + 632 < 10074) ? lo + 632 : 10074;
  for (int o = lo + tid; o < hi; o += 1024) {
    float r = 0.f; int dst;
    if (o < 4225) {
      const int a = o / 65, b = o % 65;
      #pragma unroll
      for (int h = 0; h < HD; ++h) r = fmaf(S[4912 + a*16 + h], S[5952 + b*16 + h], r);
      r *= 0.25f; dst = o;
    } else if (o < 4745) {
      const int o2 = o - 4225, a = o2 >> 3, s2 = o2 & 7;
      #pragma unroll
      for (int h = 0; h < HD; ++h) r = fmaf(S[4912 + a*16 + h], S[8160 + s2*16 + h], r);
      r *= 0.25f; dst = 8450 + o2;
    } else if (o < 5265) {
      const int o2 = o - 4745, t2 = o2 / 65, b = o2 % 65;
      #pragma unroll
      for (int h = 0; h < HD; ++h) r = fmaf(S[8032 + t2*16 + h], S[5952 + b*16 + h], r);
      r *= 0.25f; dst = 8970 + o2;
    } else if (o < 5329) {
      const int o2 = o - 5265, t2 = o2 >> 3, s2 = o2 & 7;
      #pragma unroll
      for (int h = 0; h < HD; ++h) r = fmaf(S[8032 + t2*16 + h], S[8160 + s2*16 + h], r);
      r *= 0.25f; dst = 9490 + o2;
    } else if (o < 9554) {
      const int o2 = o - 5329, a = o2 / 65, j = o2 % 65;
      #pragma unroll
      for (int h = 0; h < HD; ++h) r = fmaf(S[6992 + a*16 + h], S[3872 + h*65 + j], r);
      dst = 4225 + o2;
    } else {
      const int o2 = o - 9554, s2 = o2 / 65, j = o2 % 65;
      #pragma unroll
      for (int h = 0; h < HD; ++h) r = fmaf(S[8288 + s2*16 + h], S[3872 + h*65 + j], r);
      dst = o;
    }
    wsTab[dst] = r;
  }
}

// ---- main kernel: 1024 blocks x 512 threads; DS-pipe-minimized ----
// Cross-lane ops moved off the DS pipe: xor1/2 -> DPP, xor16/32 -> permlane
// swaps, token/target gathers -> VMEM loads (L1-resident), col-64 logit
// computed per-lane + octet-folded instead of 8 bpermute + 8 ds_read.
__global__ __launch_bounds__(512, 8) void bigram_main(
    const int* __restrict__ idx, const int* __restrict__ tgt,
    const float* __restrict__ blm, const float* __restrict__ ws,
    float* __restrict__ wsout, float* __restrict__ out)
{
  __shared__ __align__(16) float S[10074];
  __shared__ float red[8];
  const int tid = threadIdx.x;
  const int lane = tid & 63;
  const int w    = tid >> 6;                 // 0..7
  const int t    = lane >> 3;
  const int s    = lane & 7;
  const int gw = blockIdx.x * 8 + w;         // 8192 waves total
  const int gwu = __builtin_amdgcn_readfirstlane(gw);
  const int* __restrict__ idxw = idx + (gwu << 6);
  const int* __restrict__ tgtw = tgt + (gwu << 6);
  const int iv = idxw[lane];                 // element (itb*8+p) at lane itb*8+p
  const int tv = tgtw[lane];
  const float blmj  = blm[lane];
  const float blm64 = blm[64];
  const float* wsTab = ws + 16;
  {
    const float4* t4 = (const float4*)wsTab;
    float4* s4 = (float4*)S;
    for (int o = tid; o < 2518; o += 512) s4[o] = t4[o];   // 10072 floats
    if (tid < 2) S[10072 + tid] = wsTab[10072 + tid];
  }
  __syncthreads();

  float* __restrict__ outw = out + (size_t)gwu * 4160u;   // 8 itb * 520
  const bool s8   = (s == 0);
  const bool diag = (t == s);
  const unsigned vo64 = (unsigned)t * 65u + 64u;

  const float g4 = S[9490 + lane];           // G4[t][s], lane == t*8+s
  float pvl[8];
  #pragma unroll
  for (int k = 0; k < 8; ++k) pvl[k] = S[9554 + k*65 + lane];  // PVL[s=k][j=lane]
  const float pvl64s = S[9554 + s*65 + 64];  // PVL[s][64], per-lane by s
  const bool b0 = (lane & 1) != 0, b1 = (lane & 2) != 0, b2 = (lane & 4) != 0;

  float acc_lsm = 0.f, tl = 0.f;
  float eeP[8];                              // carried: prev itb exp(logits)
  float lg64P = 0.f;                         // carried: prev itb col-64 logit (by row t)
  // row-sum finisher: ee fold (xor1/2 DPP, xor4 swz) + col64 exp at diagonal
  // lanes (lane holds lg64 of row t; contributes to xor-group u=s; t==s once
  // per group) + cross-octet xor8 swz, xor16/32 permlane.
  auto reduce_row = [&](const float* ee, float lg64) {
    float k0 = b0 ? ee[1] : ee[0], s0 = b0 ? ee[0] : ee[1];
    float k1 = b0 ? ee[3] : ee[2], s1 = b0 ? ee[2] : ee[3];
    float k2 = b0 ? ee[5] : ee[4], s2 = b0 ? ee[4] : ee[5];
    float k3 = b0 ? ee[7] : ee[6], s3 = b0 ? ee[6] : ee[7];
    k0 += dppx<DPP_X1>(s0); k1 += dppx<DPP_X1>(s1);
    k2 += dppx<DPP_X1>(s2); k3 += dppx<DPP_X1>(s3);
    float m0 = b1 ? k1 : k0, t0 = b1 ? k0 : k1;
    float m1 = b1 ? k3 : k2, t1 = b1 ? k2 : k3;
    m0 += dppx<DPP_X2>(t0); m1 += dppx<DPP_X2>(t1);
    float r = b2 ? m1 : m0,  t2v = b2 ? m0 : m1;
    r += swz<SWZ_X4>(t2v);
    if (diag) r += __expf(lg64);
    r += swz<SWZ_X8>(r);
    r = permsum16(r); r = permsum32(r);
    acc_lsm += __log2f(r);
  };

  // prologue: softmax weights for itb=0
  float wsm_cur; int av_cur;
  {
    const int av0 = idxw[s];
    const int at0 = idxw[t];
    const float wr = S[at0*65 + av0] + S[8450 + at0*8 + s]
                   + S[8970 + t*65 + av0] + g4;
    const float e = (t >= s) ? __expf(wr) : 0.f;
    float sm = e + swz<SWZ_X8>(e);
    sm = permsum16(sm); sm = permsum32(sm);
    wsm_cur = __fdividef(e, sm);
    av_cur = av0;
  }

  for (int itb = 0; itb < 8; ++itb) {
    const int base  = itb * 8;
    const int basen = ((itb + 1) & 7) * 8;   // wraps on last iter (unused)
    // prefetch next itb's tokens + this itb's per-row target (VMEM, L1-hot)
    const int av_n = idxw[basen + s];
    const int at_n = idxw[basen + t];
    const int tg_c = tgtw[base + t];
    // A: LDS reads for P.V (+ col-64 M entry via av_cur)
    float ms[8];
    #pragma unroll
    for (int k = 0; k < 8; ++k) {
      const int ak = __builtin_amdgcn_readlane(iv, base + k);
      ms[k] = S[4225 + ak*65 + lane];
    }
    const float m64 = S[4225 + av_cur*65 + 64] + pvl64s;
    // B: finish previous itb's row sums (runs under A's latency)
    if (itb > 0) reduce_row(eeP, lg64P);
    // C: next itb's score chain
    const float wr_n = S[at_n*65 + av_n] + S[8450 + at_n*8 + s]
                     + S[8970 + t*65 + av_n] + g4;
    const float e_n = (t >= s) ? __expf(wr_n) : 0.f;
    // col-64 logit: per-lane product + octet fold (wei zero above diag => exact)
    float c64 = wsm_cur * m64;
    c64 += dppx<DPP_X1>(c64);
    c64 += dppx<DPP_X2>(c64);
    c64 += swz<SWZ_X4>(c64);
    const float lg64v = c64 + blm64;         // row t's col-64 logit, all octet lanes
    if (s8) outw[(unsigned)(base*65) + vo64] = lg64v;
    tl += (s8 && tg_c == 64) ? lg64v : 0.f;  // tg==64 counted once per row
    float sm_n = e_n + swz<SWZ_X8>(e_n);
    // D: P.V for this itb
    #pragma unroll
    for (int k = 0; k < 8; ++k) ms[k] += pvl[k];
    const unsigned vo = (unsigned)(base*65) + (unsigned)lane;
    #pragma unroll
    for (int tt = 0; tt < 8; ++tt) {
      float lg = blmj;                       // causal: k<=tt only (exact)
      #pragma unroll
      for (int k = 0; k <= tt; ++k) {
        const float wk = readlane_f(wsm_cur, tt*8 + k);
        lg = fmaf(wk, ms[k], lg);
      }
      outw[vo + tt*65] = lg;
      eeP[tt] = __expf(lg);
      const int tg = __builtin_amdgcn_readlane(tv, base + tt);
      tl += (lane == tg) ? lg : 0.f;         // tg<64 counted once per row
    }
    sm_n = permsum16(sm_n); sm_n = permsum32(sm_n);
    wsm_cur = __fdividef(e_n, sm_n);
    av_cur  = av_n;
    lg64P   = lg64v;
  }
  reduce_row(eeP, lg64P);                    // epilogue: itb=7
  // acc_lsm carries 8 lane-copies per row (coeff ln2/8); tl once per row
  float v = acc_lsm * (0.6931471805599453f * 0.125f) - tl;
  v += __shfl_xor(v, 1); v += __shfl_xor(v, 2);  v += __shfl_xor(v, 4);
  v += __shfl_xor(v, 8); v += __shfl_xor(v, 16); v += __shfl_xor(v, 32);
  if (lane == 0) red[w] = v;
  __syncthreads();
  if (tid == 0) {
    // poison-safe: plain store of this block's partial (no atomics)
    wsout[10112 + blockIdx.x] = red[0] + red[1] + red[2] + red[3]
                              + red[4] + red[5] + red[6] + red[7];
  }
}

// ---- final reduction: sum 1024 block partials -> loss ----
__global__ __launch_bounds__(1024) void bigram_fin2(
    const float* __restrict__ ws, float* __restrict__ out)
{
  __shared__ float r[16];
  const int tid = threadIdx.x;
  float v = ws[10112 + tid];
  v += __shfl_xor(v, 1); v += __shfl_xor(v, 2);  v += __shfl_xor(v, 4);
  v += __shfl_xor(v, 8); v += __shfl_xor(v, 16); v += __shfl_xor(v, 32);
  if ((tid & 63) == 0) r[tid >> 6] = v;
  __syncthreads();
  if (tid == 0) {
    float a = 0.f;
    #pragma unroll
    for (int i = 0; i < 16; ++i) a += r[i];
    out[NLOG] = a * (1.0f / (float)NROWS);
  }
}

extern "C" void kernel_launch(void* const* d_in, const int* in_sizes, int n_in,
                              void* d_out, int out_size, void* d_ws, size_t ws_size,
                              hipStream_t stream) {
  const int* idx = (const int*)d_in[0];
  const int* tgt = (const int*)d_in[1];
  float* ws = (float*)d_ws;
  float* out = (float*)d_out;

  bigram_tables<<<16, 1024, 0, stream>>>((const float*)d_in[2], (const float*)d_in[3],
                                         (const float*)d_in[4], (const float*)d_in[5],
                                         (const float*)d_in[6], (const float*)d_in[7],
                                         (const float*)d_in[8], (const float*)d_in[9],
                                         (const float*)d_in[10], ws);
  bigram_main<<<1024, 512, 0, stream>>>(idx, tgt, (const float*)d_in[11], ws, ws, out);
  bigram_fin2<<<1, 1024, 0, stream>>>(ws, out);
}